// Round 8
// baseline (283.030 us; speedup 1.0000x reference)
//
#include <hip/hip_runtime.h>
#include <hip/hip_bf16.h>
#include <math.h>

constexpr int B_ = 32, S_ = 128, N_ = 1024, H_ = 2, C_ = 128;
#define L2E_ 1.44269504088896340736f

typedef short  bf16x8 __attribute__((ext_vector_type(8)));
typedef float  f32x4  __attribute__((ext_vector_type(4)));
typedef ushort u16x8  __attribute__((ext_vector_type(8)));

// cheap bf16 ops (finite inputs; alpha/lo are >= 0) — avoids libcall RNE seq
__device__ __forceinline__ ushort bfr(float f) {   // round-half-up
    uint u = __builtin_bit_cast(uint, f);
    return (ushort)((u + 0x8000u) >> 16);
}
__device__ __forceinline__ ushort bft(float f) {   // truncate (hi of split)
    return (ushort)(__builtin_bit_cast(uint, f) >> 16);
}
__device__ __forceinline__ float bfhi(ushort u) {
    return __builtin_bit_cast(float, (uint)u << 16);
}

// -----------------------------------------------------------------------------
// Kernel 0 (wprep): W [H,S,C] f32 -> wth/wtl [H,C,S] bf16 hi/lo. grid(8).
// -----------------------------------------------------------------------------
__global__ __launch_bounds__(256)
void wprep_kernel(const float* __restrict__ W,
                  ushort* __restrict__ wth, ushort* __restrict__ wtl)
{
    __shared__ float sm[128][33];
    const int h = blockIdx.x >> 2, cb = (blockIdx.x & 3) * 32;
    const int tid = threadIdx.x;
    const float* Wh = W + (size_t)h * S_ * C_ + cb;
#pragma unroll
    for (int it = 0; it < 16; ++it) {
        int e = it * 256 + tid;
        int s = e >> 5, c = e & 31;
        sm[s][c] = Wh[s * C_ + c];
    }
    __syncthreads();
    const int c = tid >> 3, sg = (tid & 7) * 16;
    const size_t rowb = ((size_t)h * C_ + cb + c) * S_ + sg;
#pragma unroll
    for (int g = 0; g < 2; ++g) {
        u16x8 vh, vl;
#pragma unroll
        for (int e = 0; e < 8; ++e) {
            float v = sm[sg + g * 8 + e][c];
            ushort hh = bft(v);
            vh[e] = hh;
            vl[e] = bfr(v - bfhi(hh));
        }
        *(u16x8*)&wth[rowb + g * 8] = vh;
        *(u16x8*)&wtl[rowb + g * 8] = vl;
    }
}

// -----------------------------------------------------------------------------
// Kernel 1 (proj): z = x^T W, MFMA split-bf16 (hh+hl+lh). A-frags straight from
// x native [s][n] (16 consecutive-n lanes = full lines), in-register trunc split.
// grid (8, 32): block = 128 n x 128 c x BOTH heads; 8 waves x 16 n each; each
// wave loops h (x loaded ONCE). Writes zt[bh][c][n] bf16 + exact fp32 scores.
// -----------------------------------------------------------------------------
__global__ __launch_bounds__(512, 2)
void proj_kernel(const float* __restrict__ x,
                 const ushort* __restrict__ wth, const ushort* __restrict__ wtl,
                 const float* __restrict__ att_src, const float* __restrict__ att_dst,
                 ushort* __restrict__ zt, float* __restrict__ ssrc,
                 float* __restrict__ sdst)
{
    const int nb = blockIdx.x * 128;
    const int b  = blockIdx.y;
    const int w = threadIdx.x >> 6, lane = threadIdx.x & 63;
    const int lrow = lane & 15, lq = lane >> 4;

    f32x4 acc[2][8];
#pragma unroll
    for (int h = 0; h < 2; ++h)
#pragma unroll
        for (int ct = 0; ct < 8; ++ct)
#pragma unroll
            for (int r = 0; r < 4; ++r) acc[h][ct][r] = 0.f;

    const float* xp0 = x + (size_t)b * S_ * N_ + nb + w * 16 + lrow;

#pragma unroll
    for (int kc = 0; kc < 4; ++kc) {
        bf16x8 ah, al;
        const float* xp = xp0 + (size_t)(kc * 32 + lq * 8) * N_;
#pragma unroll
        for (int e = 0; e < 8; ++e) {
            float v = xp[(size_t)e * N_];
            ushort hi = bft(v);
            ah[e] = (short)hi;
            al[e] = (short)bfr(v - bfhi(hi));
        }
#pragma unroll
        for (int h = 0; h < 2; ++h) {
            const size_t wb = ((size_t)h * C_ + lrow) * S_ + kc * 32 + lq * 8;
#pragma unroll
            for (int ct = 0; ct < 8; ++ct) {
                bf16x8 bhv = *(const bf16x8*)(wth + wb + (size_t)ct * 16 * S_);
                bf16x8 blv = *(const bf16x8*)(wtl + wb + (size_t)ct * 16 * S_);
                acc[h][ct] = __builtin_amdgcn_mfma_f32_16x16x32_bf16(ah, bhv, acc[h][ct], 0, 0, 0);
                acc[h][ct] = __builtin_amdgcn_mfma_f32_16x16x32_bf16(ah, blv, acc[h][ct], 0, 0, 0);
                acc[h][ct] = __builtin_amdgcn_mfma_f32_16x16x32_bf16(al, bhv, acc[h][ct], 0, 0, 0);
            }
        }
    }

#pragma unroll
    for (int h = 0; h < 2; ++h) {
        const size_t bh = (size_t)(b * 2 + h);
        float asrc[8], adst[8];
#pragma unroll
        for (int ct = 0; ct < 8; ++ct) {
            asrc[ct] = att_src[h * C_ + ct * 16 + lrow];
            adst[ct] = att_dst[h * C_ + ct * 16 + lrow];
        }
        // exact fp32 scores; D row = n (lq*4+r), col = c (ct*16+lrow)
#pragma unroll
        for (int r = 0; r < 4; ++r) {
            float ps = 0.f, pd = 0.f;
#pragma unroll
            for (int ct = 0; ct < 8; ++ct) {
                ps = fmaf(acc[h][ct][r], asrc[ct], ps);
                pd = fmaf(acc[h][ct][r], adst[ct], pd);
            }
#pragma unroll
            for (int msk = 8; msk >= 1; msk >>= 1) {
                ps += __shfl_xor(ps, msk, 64);
                pd += __shfl_xor(pd, msk, 64);
            }
            if (lrow == 0) {
                int n = nb + w * 16 + lq * 4 + r;
                ssrc[bh * N_ + n] = ps;
                sdst[bh * N_ + n] = pd;
            }
        }
#pragma unroll
        for (int ct = 0; ct < 8; ++ct) {
            ushort4 v;
            v.x = bfr(acc[h][ct][0]); v.y = bfr(acc[h][ct][1]);
            v.z = bfr(acc[h][ct][2]); v.w = bfr(acc[h][ct][3]);
            *(ushort4*)&zt[(bh * C_ + ct * 16 + lrow) * N_ + nb + w * 16 + lq * 4] = v;
        }
    }
}

// -----------------------------------------------------------------------------
// Kernel 2 (attn, fused lsum): out[b,c,i] = bias[c] + sum_h sum_j alpha~ z[h,j,c]
// alpha~ = sel(e1_j >= Tr_i) ? A_i e1_j : B_i e2_j  (pre-normalized, 0.5 folded),
// with e1 = 2^(s~), e2 = 2^(0.2 s~) built in LDS and row constants computed
// in-block (2 thr/row, overlapped with chunk-0 staging).
// grid (8, B) NATURAL order (R7 lesson: XCD-packing regressed 3x — every block
// reads the whole z-slice, so spreading across XCD L2s + L3 dedup wins).
// 512 thr = 8 waves (rg x h x js); z double-buffered via global_load_lds with
// pre-swizzled source; heads+js combined via LDS epilogue.
// -----------------------------------------------------------------------------
__device__ __forceinline__ void stage_chunk512(const ushort* __restrict__ zt,
                                               uint* zstage, int b, int w,
                                               int lane, int buf, int j0)
{
#pragma unroll
    for (int it = 0; it < 4; ++it) {
        int id = (w * 4 + it) * 64 + lane;            // 0..2047
        int hh = id >> 10, c = (id >> 3) & 127, jq = id & 7;
        const uint* src = (const uint*)(zt + (((size_t)(b * 2 + hh) * C_ + c) * N_)
                                       + j0 + ((jq ^ (c & 7)) << 3));
        __builtin_amdgcn_global_load_lds(
            (const __attribute__((address_space(1))) uint*)src,
            (__attribute__((address_space(3))) uint*)&zstage[buf * 8192 + (w * 4 + it) * 256],
            16, 0, 0);
    }
}

__global__ __launch_bounds__(512, 2)
void attn_kernel(const ushort* __restrict__ zt, const float* __restrict__ ssrc,
                 const float* __restrict__ sdst, const float* __restrict__ bias,
                 float* __restrict__ out)
{
    const int bx = blockIdx.x;      // 0..7 row-block
    const int b  = blockIdx.y;

    const int tid = threadIdx.x;
    const int w = tid >> 6, lane = tid & 63;
    const int rg = w >> 2, h = (w >> 1) & 1, js = w & 1;
    const int lrow = lane & 15, lq = lane >> 4;
    const size_t bh = (size_t)(b * 2 + h);

    __shared__ char pool[128 * 132 * 4];       // exch 67.6 KB / zstage 64 KB
    __shared__ float e1s[2][N_], e2s[2][N_];   // 16 KB
    __shared__ float Lpart[512];
    __shared__ float rowA[2][128], rowB[2][128], rowTr[2][128];
    uint* zstage = (uint*)pool;
    float* exch  = (float*)pool;

    // e-tables
#pragma unroll
    for (int it = 0; it < 4; ++it) {
        int e = it * 512 + tid;
        int hh = e >> 10, j = e & 1023;
        float sv = ssrc[((size_t)b * 2 + hh) * N_ + j] * L2E_;
        e1s[hh][j] = exp2f(sv);
        e2s[hh][j] = exp2f(0.2f * sv);
    }
    __syncthreads();

    stage_chunk512(zt, zstage, b, w, lane, 0, 0);   // async; hides under lsum

    // fused lsum: 2 threads per (head,row)
    const int rid = tid & 255;
    const int hh2 = rid >> 7, iloc = rid & 127;
    const int jh = tid >> 8;
    const float dt = sdst[((size_t)b * 2 + hh2) * N_ + bx * 128 + iloc] * L2E_;
    const float pA = exp2f(dt), pB = exp2f(0.2f * dt), Tr = exp2f(-dt);
    {
        float L = 0.f;
        const int j0 = jh * 512;
        for (int j = j0; j < j0 + 512; j += 4) {
#pragma unroll
            for (int u = 0; u < 4; ++u) {
                float a = e1s[hh2][j + u], bb = e2s[hh2][j + u];
                L += (a >= Tr) ? pA * a : pB * bb;
            }
        }
        Lpart[tid] = L;
    }
    __syncthreads();                                 // also drains chunk 0
    if (tid < 256) {
        float inv = 0.5f / (Lpart[tid] + Lpart[tid + 256]);
        rowA[hh2][iloc] = pA * inv;
        rowB[hh2][iloc] = pB * inv;
        rowTr[hh2][iloc] = Tr;
    }
    __syncthreads();

    float A4[4], B4[4], T4[4];
#pragma unroll
    for (int t = 0; t < 4; ++t) {
        int i = rg * 64 + t * 16 + lrow;
        A4[t] = rowA[h][i]; B4[t] = rowB[h][i]; T4[t] = rowTr[h][i];
    }

    f32x4 acc[4][8];
#pragma unroll
    for (int t = 0; t < 4; ++t)
#pragma unroll
        for (int ct = 0; ct < 8; ++ct)
#pragma unroll
            for (int r = 0; r < 4; ++r) acc[t][ct][r] = 0.f;

    // invariant part of the swizzled LDS read offset (ct*16 ≡ 0 mod 8)
    const int lds_base = h * 16384 + lrow * 128 + (((js * 4 + lq) ^ (lrow & 7)) << 4);

    int buf = 0;
    for (int jc = 0; jc < 16; ++jc) {
        if (jc < 15) stage_chunk512(zt, zstage, b, w, lane, buf ^ 1, (jc + 1) * 64);
        const int j32 = jc * 64 + js * 32;

        float4 e1a = *(const float4*)&e1s[h][j32 + lq * 8];
        float4 e1b = *(const float4*)&e1s[h][j32 + lq * 8 + 4];
        float4 e2a = *(const float4*)&e2s[h][j32 + lq * 8];
        float4 e2b = *(const float4*)&e2s[h][j32 + lq * 8 + 4];
        float ev1[8] = {e1a.x, e1a.y, e1a.z, e1a.w, e1b.x, e1b.y, e1b.z, e1b.w};
        float ev2[8] = {e2a.x, e2a.y, e2a.z, e2a.w, e2b.x, e2b.y, e2b.z, e2b.w};

        const char* zb = (const char*)zstage + buf * 32768 + lds_base;
        bf16x8 bf[8];
#pragma unroll
        for (int ct = 0; ct < 8; ++ct)
            bf[ct] = *(const bf16x8*)(zb + ct * 2048);

#pragma unroll
        for (int t = 0; t < 4; ++t) {
            bf16x8 af;
#pragma unroll
            for (int r = 0; r < 8; ++r) {
                float al = (ev1[r] >= T4[t]) ? A4[t] * ev1[r] : B4[t] * ev2[r];
                af[r] = (short)bfr(al);
            }
#pragma unroll
            for (int ct = 0; ct < 8; ++ct)
                acc[t][ct] = __builtin_amdgcn_mfma_f32_16x16x32_bf16(af, bf[ct], acc[t][ct], 0, 0, 0);
        }
        __syncthreads();
        buf ^= 1;
    }

    // epilogue: accumulate the 4 (h,js) wave-groups into exch[c][132-padded i]
    const int grp = w & 3;
#pragma unroll 1
    for (int p = 0; p < 4; ++p) {
        if (grp == p) {
#pragma unroll
            for (int t = 0; t < 4; ++t)
#pragma unroll
                for (int ct = 0; ct < 8; ++ct) {
                    int c = ct * 16 + lrow;
                    int i = rg * 64 + t * 16 + lq * 4;
                    float* dst = &exch[c * 132 + i];
                    if (p == 0) {
                        *(float4*)dst = make_float4(acc[t][ct][0], acc[t][ct][1],
                                                    acc[t][ct][2], acc[t][ct][3]);
                    } else {
                        float4 v = *(const float4*)dst;
                        v.x += acc[t][ct][0]; v.y += acc[t][ct][1];
                        v.z += acc[t][ct][2]; v.w += acc[t][ct][3];
                        *(float4*)dst = v;
                    }
                }
        }
        __syncthreads();
    }

    const int cl = tid >> 5, il = (tid & 31) * 4;
#pragma unroll
    for (int it = 0; it < 8; ++it) {
        int c = it * 16 + cl;
        float bvv = bias[c];
        float4 v = *(const float4*)&exch[c * 132 + il];
        v.x += bvv; v.y += bvv; v.z += bvv; v.w += bvv;
        *(float4*)&out[((size_t)b * C_ + c) * N_ + bx * 128 + il] = v;
    }
}

extern "C" void kernel_launch(void* const* d_in, const int* in_sizes, int n_in,
                              void* d_out, int out_size, void* d_ws, size_t ws_size,
                              hipStream_t stream) {
    const float* x       = (const float*)d_in[0];
    const float* W       = (const float*)d_in[1];
    const float* att_src = (const float*)d_in[2];
    const float* att_dst = (const float*)d_in[3];
    const float* bias    = (const float*)d_in[4];
    float* out = (float*)d_out;

    ushort* wth = (ushort*)d_ws;                              // 2*128*128
    ushort* wtl = wth + (size_t)H_ * C_ * S_;
    ushort* zt  = wtl + (size_t)H_ * C_ * S_;                 // 64*128*1024 bf16
    float* ssrc = (float*)(zt + (size_t)B_ * H_ * C_ * N_);
    float* sdst = ssrc + (size_t)B_ * H_ * N_;

    wprep_kernel<<<dim3(8), 256, 0, stream>>>(W, wth, wtl);
    proj_kernel<<<dim3(8, 32), 512, 0, stream>>>(
        x, wth, wtl, att_src, att_dst, zt, ssrc, sdst);
    attn_kernel<<<dim3(8, B_), 512, 0, stream>>>(zt, ssrc, sdst, bias, out);
}

// Round 9
// 186.491 us; speedup vs baseline: 1.5177x; 1.5177x over previous
//
#include <hip/hip_runtime.h>
#include <hip/hip_bf16.h>
#include <math.h>

constexpr int B_ = 32, S_ = 128, N_ = 1024, H_ = 2, C_ = 128;
#define L2E_ 1.44269504088896340736f

typedef short  bf16x8 __attribute__((ext_vector_type(8)));
typedef float  f32x4  __attribute__((ext_vector_type(4)));
typedef ushort u16x8  __attribute__((ext_vector_type(8)));

__device__ __forceinline__ ushort f2bf(float f) {   // RNE (libcall) — R4 verbatim
    __hip_bfloat16 h = __float2bfloat16(f);
    return __builtin_bit_cast(ushort, h);
}
// cheap bf16 ops (finite inputs) — used in wprep/proj only
__device__ __forceinline__ ushort bfr(float f) {   // round-half-up
    uint u = __builtin_bit_cast(uint, f);
    return (ushort)((u + 0x8000u) >> 16);
}
__device__ __forceinline__ ushort bft(float f) {   // truncate (hi of split)
    return (ushort)(__builtin_bit_cast(uint, f) >> 16);
}
__device__ __forceinline__ float bfhi(ushort u) {
    return __builtin_bit_cast(float, (uint)u << 16);
}

// -----------------------------------------------------------------------------
// Kernel 0 (wprep): W [H,S,C] f32 -> wth/wtl [H,C,S] bf16 hi/lo. grid(8). [R6]
// -----------------------------------------------------------------------------
__global__ __launch_bounds__(256)
void wprep_kernel(const float* __restrict__ W,
                  ushort* __restrict__ wth, ushort* __restrict__ wtl)
{
    __shared__ float sm[128][33];
    const int h = blockIdx.x >> 2, cb = (blockIdx.x & 3) * 32;
    const int tid = threadIdx.x;
    const float* Wh = W + (size_t)h * S_ * C_ + cb;
#pragma unroll
    for (int it = 0; it < 16; ++it) {
        int e = it * 256 + tid;
        int s = e >> 5, c = e & 31;
        sm[s][c] = Wh[s * C_ + c];
    }
    __syncthreads();
    const int c = tid >> 3, sg = (tid & 7) * 16;
    const size_t rowb = ((size_t)h * C_ + cb + c) * S_ + sg;
#pragma unroll
    for (int g = 0; g < 2; ++g) {
        u16x8 vh, vl;
#pragma unroll
        for (int e = 0; e < 8; ++e) {
            float v = sm[sg + g * 8 + e][c];
            ushort hh = bft(v);
            vh[e] = hh;
            vl[e] = bfr(v - bfhi(hh));
        }
        *(u16x8*)&wth[rowb + g * 8] = vh;
        *(u16x8*)&wtl[rowb + g * 8] = vl;
    }
}

// -----------------------------------------------------------------------------
// Kernel 1 (proj): z = x^T W, MFMA split-bf16 (hh+hl+lh). [R6: x read once]
// -----------------------------------------------------------------------------
__global__ __launch_bounds__(512, 2)
void proj_kernel(const float* __restrict__ x,
                 const ushort* __restrict__ wth, const ushort* __restrict__ wtl,
                 const float* __restrict__ att_src, const float* __restrict__ att_dst,
                 ushort* __restrict__ zt, float* __restrict__ ssrc,
                 float* __restrict__ sdst)
{
    const int nb = blockIdx.x * 128;
    const int b  = blockIdx.y;
    const int w = threadIdx.x >> 6, lane = threadIdx.x & 63;
    const int lrow = lane & 15, lq = lane >> 4;

    f32x4 acc[2][8];
#pragma unroll
    for (int h = 0; h < 2; ++h)
#pragma unroll
        for (int ct = 0; ct < 8; ++ct)
#pragma unroll
            for (int r = 0; r < 4; ++r) acc[h][ct][r] = 0.f;

    const float* xp0 = x + (size_t)b * S_ * N_ + nb + w * 16 + lrow;

#pragma unroll
    for (int kc = 0; kc < 4; ++kc) {
        bf16x8 ah, al;
        const float* xp = xp0 + (size_t)(kc * 32 + lq * 8) * N_;
#pragma unroll
        for (int e = 0; e < 8; ++e) {
            float v = xp[(size_t)e * N_];
            ushort hi = bft(v);
            ah[e] = (short)hi;
            al[e] = (short)bfr(v - bfhi(hi));
        }
#pragma unroll
        for (int h = 0; h < 2; ++h) {
            const size_t wb = ((size_t)h * C_ + lrow) * S_ + kc * 32 + lq * 8;
#pragma unroll
            for (int ct = 0; ct < 8; ++ct) {
                bf16x8 bhv = *(const bf16x8*)(wth + wb + (size_t)ct * 16 * S_);
                bf16x8 blv = *(const bf16x8*)(wtl + wb + (size_t)ct * 16 * S_);
                acc[h][ct] = __builtin_amdgcn_mfma_f32_16x16x32_bf16(ah, bhv, acc[h][ct], 0, 0, 0);
                acc[h][ct] = __builtin_amdgcn_mfma_f32_16x16x32_bf16(ah, blv, acc[h][ct], 0, 0, 0);
                acc[h][ct] = __builtin_amdgcn_mfma_f32_16x16x32_bf16(al, bhv, acc[h][ct], 0, 0, 0);
            }
        }
    }

#pragma unroll
    for (int h = 0; h < 2; ++h) {
        const size_t bh = (size_t)(b * 2 + h);
        float asrc[8], adst[8];
#pragma unroll
        for (int ct = 0; ct < 8; ++ct) {
            asrc[ct] = att_src[h * C_ + ct * 16 + lrow];
            adst[ct] = att_dst[h * C_ + ct * 16 + lrow];
        }
#pragma unroll
        for (int r = 0; r < 4; ++r) {
            float ps = 0.f, pd = 0.f;
#pragma unroll
            for (int ct = 0; ct < 8; ++ct) {
                ps = fmaf(acc[h][ct][r], asrc[ct], ps);
                pd = fmaf(acc[h][ct][r], adst[ct], pd);
            }
#pragma unroll
            for (int msk = 8; msk >= 1; msk >>= 1) {
                ps += __shfl_xor(ps, msk, 64);
                pd += __shfl_xor(pd, msk, 64);
            }
            if (lrow == 0) {
                int n = nb + w * 16 + lq * 4 + r;
                ssrc[bh * N_ + n] = ps;
                sdst[bh * N_ + n] = pd;
            }
        }
#pragma unroll
        for (int ct = 0; ct < 8; ++ct) {
            ushort4 v;
            v.x = bfr(acc[h][ct][0]); v.y = bfr(acc[h][ct][1]);
            v.z = bfr(acc[h][ct][2]); v.w = bfr(acc[h][ct][3]);
            *(ushort4*)&zt[(bh * C_ + ct * 16 + lrow) * N_ + nb + w * 16 + lq * 4] = v;
        }
    }
}

// -----------------------------------------------------------------------------
// Kernel 2 (lsum): [R4-sub VERBATIM] e-domain constants. e1=2^sv, e2=2^(0.2sv);
// per row i: L = sum_j sel(e1_j>=Tr)?pA*e1:pB*e2; A=0.5pA/L, B=0.5pB/L, Tr=2^-dt.
// -----------------------------------------------------------------------------
__global__ __launch_bounds__(256)
void lsum_kernel(const float* __restrict__ ssrc, const float* __restrict__ sdst,
                 float* __restrict__ e1t, float* __restrict__ e2t,
                 float* __restrict__ Aar, float* __restrict__ Bar,
                 float* __restrict__ Trar)
{
    const int bh = blockIdx.y, ib = blockIdx.x * 256;
    const int tid = threadIdx.x;
    __shared__ float e1s[N_], e2s[N_];

#pragma unroll
    for (int it = 0; it < 4; ++it) {
        int j = it * 256 + tid;
        float sv = ssrc[(size_t)bh * N_ + j] * L2E_;
        e1s[j] = exp2f(sv);
        e2s[j] = exp2f(0.2f * sv);
    }
    __syncthreads();

    const int i = ib + tid;
    e1t[(size_t)bh * N_ + i] = e1s[i];
    e2t[(size_t)bh * N_ + i] = e2s[i];

    const float dt = sdst[(size_t)bh * N_ + i] * L2E_;
    const float pA = exp2f(dt), pB = exp2f(0.2f * dt), Tr = exp2f(-dt);

    float l0 = 0.f, l1 = 0.f, l2 = 0.f, l3 = 0.f;
    for (int j = 0; j < N_; j += 4) {
        float a0 = e1s[j],     a1 = e1s[j + 1], a2 = e1s[j + 2], a3 = e1s[j + 3];
        float b0 = e2s[j],     b1 = e2s[j + 1], b2 = e2s[j + 2], b3 = e2s[j + 3];
        l0 += (a0 >= Tr) ? pA * a0 : pB * b0;
        l1 += (a1 >= Tr) ? pA * a1 : pB * b1;
        l2 += (a2 >= Tr) ? pA * a2 : pB * b2;
        l3 += (a3 >= Tr) ? pA * a3 : pB * b3;
    }
    const float inv = 0.5f / ((l0 + l1) + (l2 + l3));   // fold head-mean 0.5
    Aar[(size_t)bh * N_ + i]  = pA * inv;
    Bar[(size_t)bh * N_ + i]  = pB * inv;
    Trar[(size_t)bh * N_ + i] = Tr;
}

// -----------------------------------------------------------------------------
// Kernel 3 (attn): [R4-sub VERBATIM — measured fast in R5]
// -----------------------------------------------------------------------------
__device__ __forceinline__ void stage_chunk512(const ushort* __restrict__ zt,
                                               uint* zstage, int b, int w,
                                               int lane, int buf, int j0)
{
#pragma unroll
    for (int it = 0; it < 4; ++it) {
        int id = (w * 4 + it) * 64 + lane;            // 0..2047
        int hh = id >> 10, c = (id >> 3) & 127, jq = id & 7;
        const uint* src = (const uint*)(zt + (((size_t)(b * 2 + hh) * C_ + c) * N_)
                                       + j0 + ((jq ^ (c & 7)) << 3));
        __builtin_amdgcn_global_load_lds(
            (const __attribute__((address_space(1))) uint*)src,
            (__attribute__((address_space(3))) uint*)&zstage[buf * 8192 + (w * 4 + it) * 256],
            16, 0, 0);
    }
}

__global__ __launch_bounds__(512, 2)
void attn_kernel(const ushort* __restrict__ zt,
                 const float* __restrict__ e1t, const float* __restrict__ e2t,
                 const float* __restrict__ Aar, const float* __restrict__ Bar,
                 const float* __restrict__ Trar, const float* __restrict__ bias,
                 float* __restrict__ out)
{
    // XCD-packed decode: all 8 row-blocks of a batch land on one XCD
    const int id0 = blockIdx.x;
    const int xcd = id0 & 7, k = id0 >> 3;
    const int b = xcd * 4 + (k >> 3), bx = k & 7;

    const int tid = threadIdx.x;
    const int w = tid >> 6, lane = tid & 63;
    const int rg = w >> 2, h = (w >> 1) & 1, js = w & 1;
    const int lrow = lane & 15, lq = lane >> 4;
    const int rowbase = bx * 128 + rg * 64;
    const size_t bh = (size_t)(b * 2 + h);

    __shared__ char pool[128 * 132 * 4];      // exch 67.5 KB; zstage 64 KB overlay
    __shared__ float e1s[2][N_], e2s[2][N_];  // 16 KB
    uint* zstage = (uint*)pool;
    float* exch  = (float*)pool;

    float A4[4], B4[4], T4[4];
#pragma unroll
    for (int t = 0; t < 4; ++t) {
        int i = rowbase + t * 16 + lrow;
        A4[t] = Aar[bh * N_ + i];
        B4[t] = Bar[bh * N_ + i];
        T4[t] = Trar[bh * N_ + i];
    }
#pragma unroll
    for (int it = 0; it < 4; ++it) {
        int e = it * 512 + tid;
        int hh = e >> 10, j = e & 1023;
        e1s[hh][j] = e1t[((size_t)b * 2 + hh) * N_ + j];
        e2s[hh][j] = e2t[((size_t)b * 2 + hh) * N_ + j];
    }
    stage_chunk512(zt, zstage, b, w, lane, 0, 0);
    __syncthreads();

    f32x4 acc[4][8];
#pragma unroll
    for (int t = 0; t < 4; ++t)
#pragma unroll
        for (int ct = 0; ct < 8; ++ct)
#pragma unroll
            for (int r = 0; r < 4; ++r) acc[t][ct][r] = 0.f;

    int buf = 0;
    for (int jc = 0; jc < 16; ++jc) {
        if (jc < 15) stage_chunk512(zt, zstage, b, w, lane, buf ^ 1, (jc + 1) * 64);
        const int j32 = jc * 64 + js * 32;

        float4 e1a = *(const float4*)&e1s[h][j32 + lq * 8];
        float4 e1b = *(const float4*)&e1s[h][j32 + lq * 8 + 4];
        float4 e2a = *(const float4*)&e2s[h][j32 + lq * 8];
        float4 e2b = *(const float4*)&e2s[h][j32 + lq * 8 + 4];
        float ev1[8] = {e1a.x, e1a.y, e1a.z, e1a.w, e1b.x, e1b.y, e1b.z, e1b.w};
        float ev2[8] = {e2a.x, e2a.y, e2a.z, e2a.w, e2b.x, e2b.y, e2b.z, e2b.w};

        bf16x8 bf[8];
#pragma unroll
        for (int ct = 0; ct < 8; ++ct) {
            int c = ct * 16 + lrow;
            int off = buf * 32768 + h * 16384 + c * 128 + ((((js * 4) + lq) ^ (c & 7)) << 4);
            bf[ct] = *(const bf16x8*)((const char*)zstage + off);
        }
#pragma unroll
        for (int t = 0; t < 4; ++t) {
            bf16x8 af;
#pragma unroll
            for (int r = 0; r < 8; ++r) {
                float al = (ev1[r] >= T4[t]) ? A4[t] * ev1[r] : B4[t] * ev2[r];
                af[r] = (short)f2bf(al);
            }
#pragma unroll
            for (int ct = 0; ct < 8; ++ct)
                acc[t][ct] = __builtin_amdgcn_mfma_f32_16x16x32_bf16(af, bf[ct], acc[t][ct], 0, 0, 0);
        }
        __syncthreads();
        buf ^= 1;
    }

    // epilogue: accumulate 4 wave-groups (h,js) into exch[c][132-padded i]
    const int grp = w & 3;
#pragma unroll 1
    for (int p = 0; p < 4; ++p) {
        if (grp == p) {
#pragma unroll
            for (int t = 0; t < 4; ++t)
#pragma unroll
                for (int ct = 0; ct < 8; ++ct) {
                    int c = ct * 16 + lrow;
                    int i = rg * 64 + t * 16 + lq * 4;
                    float* dst = &exch[c * 132 + i];
                    if (p == 0) {
                        *(float4*)dst = make_float4(acc[t][ct][0], acc[t][ct][1],
                                                    acc[t][ct][2], acc[t][ct][3]);
                    } else {
                        float4 v = *(const float4*)dst;
                        v.x += acc[t][ct][0]; v.y += acc[t][ct][1];
                        v.z += acc[t][ct][2]; v.w += acc[t][ct][3];
                        *(float4*)dst = v;
                    }
                }
        }
        __syncthreads();
    }

    const int cl = tid >> 5, il = (tid & 31) * 4;
#pragma unroll
    for (int it = 0; it < 8; ++it) {
        int c = it * 16 + cl;
        float bvv = bias[c];
        float4 v = *(const float4*)&exch[c * 132 + il];
        v.x += bvv; v.y += bvv; v.z += bvv; v.w += bvv;
        *(float4*)&out[((size_t)b * C_ + c) * N_ + bx * 128 + il] = v;
    }
}

extern "C" void kernel_launch(void* const* d_in, const int* in_sizes, int n_in,
                              void* d_out, int out_size, void* d_ws, size_t ws_size,
                              hipStream_t stream) {
    const float* x       = (const float*)d_in[0];
    const float* W       = (const float*)d_in[1];
    const float* att_src = (const float*)d_in[2];
    const float* att_dst = (const float*)d_in[3];
    const float* bias    = (const float*)d_in[4];
    float* out = (float*)d_out;

    ushort* wth = (ushort*)d_ws;                              // 2*128*128
    ushort* wtl = wth + (size_t)H_ * C_ * S_;
    ushort* zt  = wtl + (size_t)H_ * C_ * S_;                 // 64*128*1024 bf16
    float* ssrc = (float*)(zt + (size_t)B_ * H_ * C_ * N_);
    float* sdst = ssrc + (size_t)B_ * H_ * N_;
    float* e1t  = sdst + (size_t)B_ * H_ * N_;
    float* e2t  = e1t + (size_t)B_ * H_ * N_;
    float* Aar  = e2t + (size_t)B_ * H_ * N_;
    float* Bar  = Aar + (size_t)B_ * H_ * N_;
    float* Trar = Bar + (size_t)B_ * H_ * N_;

    wprep_kernel<<<dim3(8), 256, 0, stream>>>(W, wth, wtl);
    proj_kernel<<<dim3(8, 32), 512, 0, stream>>>(
        x, wth, wtl, att_src, att_dst, zt, ssrc, sdst);
    lsum_kernel<<<dim3(4, B_ * H_), 256, 0, stream>>>(
        ssrc, sdst, e1t, e2t, Aar, Bar, Trar);
    attn_kernel<<<dim3(256), 512, 0, stream>>>(
        zt, e1t, e2t, Aar, Bar, Trar, bias, out);
}